// Round 1
// baseline (78.791 us; speedup 1.0000x reference)
//
#include <hip/hip_runtime.h>

#define BS   2
#define NCTX 2048
#define NH   8
#define WD   32
#define NTOK 512

static constexpr int   R_ROWS  = 8;               // rows per wave
static constexpr int   J_SPLIT = 8;               // j-chunks across lanes
static constexpr int   J_CHUNK = NTOK / J_SPLIT;  // 64
static constexpr float SCALE   = 0.04419417382415922f; // 1/sqrt(512)

__device__ __forceinline__ void load_rows(const float* __restrict__ qb,
                                          const float* __restrict__ vb,
                                          int tok,
                                          float4 qd[8], float4 vd[8]) {
  const float4* qr = (const float4*)(qb + (size_t)tok * (NH * WD));
  const float4* vr = (const float4*)(vb + (size_t)tok * (NH * WD));
#pragma unroll
  for (int i = 0; i < 8; ++i) { qd[i] = qr[i]; vd[i] = vr[i]; }
}

__device__ __forceinline__ void body(const float4 qd[8], const float4 vd[8],
                                     const float kg[WD], float& l, float acc[WD]) {
  // L1 distance, 4 independent chains to break the add dependency
  float d0 = 0.f, d1 = 0.f, d2 = 0.f, d3 = 0.f;
#pragma unroll
  for (int i = 0; i < 8; ++i) {
    d0 += fabsf(kg[4*i+0] - qd[i].x);
    d1 += fabsf(kg[4*i+1] - qd[i].y);
    d2 += fabsf(kg[4*i+2] - qd[i].z);
    d3 += fabsf(kg[4*i+3] - qd[i].w);
  }
  float d = (d0 + d1) + (d2 + d3);
  float p = __expf(-SCALE * d);   // no max-shift needed: d in [0, ~350]
  l += p;
#pragma unroll
  for (int i = 0; i < 8; ++i) {
    acc[4*i+0] = fmaf(p, vd[i].x, acc[4*i+0]);
    acc[4*i+1] = fmaf(p, vd[i].y, acc[4*i+1]);
    acc[4*i+2] = fmaf(p, vd[i].z, acc[4*i+2]);
    acc[4*i+3] = fmaf(p, vd[i].w, acc[4*i+3]);
  }
}

__global__ void __launch_bounds__(256)
l1attn_sparse_kernel(const float* __restrict__ q, const float* __restrict__ k,
                     const float* __restrict__ v, const int* __restrict__ indx,
                     float* __restrict__ out) {
  const int wave = threadIdx.x >> 6;
  const int lane = threadIdx.x & 63;
  const int task = blockIdx.x * 4 + wave;   // [0, 1024)
  const int bh   = task >> 6;               // [0, 16)
  const int rg   = task & 63;               // row-group within (b,h)
  const int b    = bh >> 3;
  const int h    = bh & 7;
  const int r    = lane & (R_ROWS - 1);     // 0..7 row within group
  const int jh   = lane >> 3;               // 0..7 j-chunk
  const int s    = rg * R_ROWS + r;         // gathered row index [0,512)

  const float* qb = q + ((size_t)b * NCTX * NH + h) * WD;
  const float* kb = k + ((size_t)b * NCTX * NH + h) * WD;
  const float* vb = v + ((size_t)b * NCTX * NH + h) * WD;

  // K row for this lane's output row s (row index keys on k per the einsum)
  float kg[WD];
  {
    const int ktok = indx[s];
    const float4* kr = (const float4*)(kb + (size_t)ktok * (NH * WD));
#pragma unroll
    for (int i = 0; i < 8; ++i) {
      float4 t = kr[i];
      kg[4*i+0] = t.x; kg[4*i+1] = t.y; kg[4*i+2] = t.z; kg[4*i+3] = t.w;
    }
  }

  float acc[WD];
#pragma unroll
  for (int i = 0; i < WD; ++i) acc[i] = 0.f;
  float l = 0.f;

  const int jbase = jh * J_CHUNK;

  // software-pipelined j loop: double-buffered q/v rows, indx prefetched ahead
  float4 q0[8], v0[8], q1[8], v1[8];
  int tokn = indx[jbase + 1];
  {
    int tokc = indx[jbase];
    load_rows(qb, vb, tokc, q0, v0);
  }

  for (int it = 0; it < J_CHUNK; it += 2) {
    const int i2 = (it + 2 < J_CHUNK) ? it + 2 : J_CHUNK - 1;
    const int i3 = (it + 3 < J_CHUNK) ? it + 3 : J_CHUNK - 1;
    const int tok2 = indx[jbase + i2];
    const int tok3 = indx[jbase + i3];

    load_rows(qb, vb, tokn, q1, v1);   // rows for it+1
    body(q0, v0, kg, l, acc);          // compute it

    load_rows(qb, vb, tok2, q0, v0);   // rows for it+2
    body(q1, v1, kg, l, acc);          // compute it+1

    tokn = tok3;
  }

  // butterfly reduce across the 8 jh chunks (lane bits 3..5)
#pragma unroll
  for (int m = 8; m < 64; m <<= 1) {
    l += __shfl_xor(l, m, 64);
#pragma unroll
    for (int i = 0; i < WD; ++i) acc[i] += __shfl_xor(acc[i], m, 64);
  }

  if (jh == 0) {
    const float inv = 1.0f / l;
    float* orow = out + (((size_t)b * NTOK + s) * NH + h) * WD;
#pragma unroll
    for (int i = 0; i < 8; ++i) {
      float4 o;
      o.x = acc[4*i+0] * inv;
      o.y = acc[4*i+1] * inv;
      o.z = acc[4*i+2] * inv;
      o.w = acc[4*i+3] * inv;
      ((float4*)orow)[i] = o;
    }
  }
}

extern "C" void kernel_launch(void* const* d_in, const int* in_sizes, int n_in,
                              void* d_out, int out_size, void* d_ws, size_t ws_size,
                              hipStream_t stream) {
  const float* q    = (const float*)d_in[0];
  const float* k    = (const float*)d_in[1];
  const float* v    = (const float*)d_in[2];
  const int*   indx = (const int*)d_in[3];
  float*       out  = (float*)d_out;

  dim3 grid(256), block(256);
  hipLaunchKernelGGL(l1attn_sparse_kernel, grid, block, 0, stream,
                     q, k, v, indx, out);
}

// Round 2
// 55.458 us; speedup vs baseline: 1.4207x; 1.4207x over previous
//
#include <hip/hip_runtime.h>

#define BS   2
#define NCTX 2048
#define NH   8
#define WD   32
#define NTOK 512

static constexpr float SCALE = 0.04419417382415922f; // 1/sqrt(512)

// wave = 32 rows x one 32-j chunk; lane = whalf*32 + r
// block = 1024 threads = 16 waves = all 16 j-chunks of one 32-row group
// grid  = 16 (b,h) planes x 16 row-groups = 256 blocks (1 per CU)

__device__ __forceinline__ void load8(const float* __restrict__ base, int tok,
                                      float4 dst[4]) {
  const float4* p = (const float4*)(base + (size_t)tok * (NH * WD));
#pragma unroll
  for (int i = 0; i < 4; ++i) dst[i] = p[i];
}

__device__ __forceinline__ void body(const float4 qd[4], const float4 vd[4],
                                     const float kg[16], float& l, float acc[16]) {
  float d0 = 0.f, d1 = 0.f, d2 = 0.f, d3 = 0.f;
#pragma unroll
  for (int i = 0; i < 4; ++i) {
    d0 += fabsf(kg[4*i+0] - qd[i].x);
    d1 += fabsf(kg[4*i+1] - qd[i].y);
    d2 += fabsf(kg[4*i+2] - qd[i].z);
    d3 += fabsf(kg[4*i+3] - qd[i].w);
  }
  float d = (d0 + d1) + (d2 + d3);
  d += __shfl_xor(d, 32, 64);          // combine the two w-halves of this row
  float p = __expf(-SCALE * d);        // d in [0, ~350]: no max-shift needed
  l += p;
#pragma unroll
  for (int i = 0; i < 4; ++i) {
    acc[4*i+0] = fmaf(p, vd[i].x, acc[4*i+0]);
    acc[4*i+1] = fmaf(p, vd[i].y, acc[4*i+1]);
    acc[4*i+2] = fmaf(p, vd[i].z, acc[4*i+2]);
    acc[4*i+3] = fmaf(p, vd[i].w, acc[4*i+3]);
  }
}

__global__ void __launch_bounds__(1024, 4)
l1attn_v2(const float* __restrict__ q, const float* __restrict__ k,
          const float* __restrict__ v, const int* __restrict__ indx,
          float* __restrict__ out) {
  __shared__ int   indxS[NTOK];
  __shared__ float accS[32 * 33];     // [row][w], stride 33 -> 2-way bank alias (free)
  __shared__ float lS[32];

  const int tid = threadIdx.x;

  // stage indx + zero the block accumulators
  if (tid < NTOK) indxS[tid] = indx[tid];
  for (int i = tid; i < 32 * 33; i += 1024) accS[i] = 0.f;
  if (tid < 32) lS[tid] = 0.f;
  __syncthreads();

  const int wave  = __builtin_amdgcn_readfirstlane(tid >> 6); // 0..15 = j-chunk
  const int lane  = tid & 63;
  const int whalf = lane >> 5;        // 0/1: which 16 of the 32 w's
  const int r     = lane & 31;        // row within group

  const int bh = blockIdx.x >> 4;     // 0..15
  const int g  = blockIdx.x & 15;     // row-group
  const int b  = bh >> 3;
  const int h  = bh & 7;
  const int s  = g * 32 + r;          // gathered row index [0,512)

  const float* qb = q + ((size_t)b * NCTX * NH + h) * WD + whalf * 16;
  const float* vb = v + ((size_t)b * NCTX * NH + h) * WD + whalf * 16;
  const float* kb = k + ((size_t)b * NCTX * NH + h) * WD + whalf * 16;

  // this lane's half of the K row for row s (rows key on k per the einsum)
  float kg[16];
  {
    const float4* kr = (const float4*)(kb + (size_t)indxS[s] * (NH * WD));
#pragma unroll
    for (int i = 0; i < 4; ++i) {
      float4 t = kr[i];
      kg[4*i+0] = t.x; kg[4*i+1] = t.y; kg[4*i+2] = t.z; kg[4*i+3] = t.w;
    }
  }

  float acc[16];
#pragma unroll
  for (int i = 0; i < 16; ++i) acc[i] = 0.f;
  float l = 0.f;

  const int jb = wave * 32;

  // ping-pong double buffer over this wave's 32 j's
  float4 q0[4], v0[4], q1[4], v1[4];
  int tokB = indxS[jb + 1];
  load8(qb, indxS[jb], q0);
  load8(vb, indxS[jb], v0);

  for (int jj = 0; jj < 32; jj += 2) {
    const int tokC = indxS[jb + ((jj + 2) & 31)];   // wrap: final prefetch unused
    const int tokD = indxS[jb + ((jj + 3) & 31)];

    load8(qb, tokB, q1);
    load8(vb, tokB, v1);
    body(q0, v0, kg, l, acc);

    load8(qb, tokC, q0);
    load8(vb, tokC, v0);
    body(q1, v1, kg, l, acc);

    tokB = tokD;
  }

  // combine the 16 j-chunk partials in LDS
#pragma unroll
  for (int i = 0; i < 16; ++i)
    atomicAdd(&accS[r * 33 + whalf * 16 + i], acc[i]);
  if (whalf == 0) atomicAdd(&lS[r], l);
  __syncthreads();

  // write out: thread -> (row rr, w ww), coalesced 128B per row
  {
    const int rr = tid >> 5;
    const int ww = tid & 31;
    const float res = accS[rr * 33 + ww] / lS[rr];
    const int ss = g * 32 + rr;
    out[(((size_t)b * NTOK + ss) * NH + h) * WD + ww] = res;
  }
}

extern "C" void kernel_launch(void* const* d_in, const int* in_sizes, int n_in,
                              void* d_out, int out_size, void* d_ws, size_t ws_size,
                              hipStream_t stream) {
  const float* q    = (const float*)d_in[0];
  const float* k    = (const float*)d_in[1];
  const float* v    = (const float*)d_in[2];
  const int*   indx = (const int*)d_in[3];
  float*       out  = (float*)d_out;

  dim3 grid(256), block(1024);
  hipLaunchKernelGGL(l1attn_v2, grid, block, 0, stream, q, k, v, indx, out);
}